// Round 13
// baseline (139.190 us; speedup 1.0000x reference)
//
#include <hip/hip_runtime.h>
#include <hip/hip_bf16.h>

// (B,S,H,D) = (2,2048,16,64), fp32 in/out, int32 mask (True -> -inf).
#define BB 2
#define SS 2048
#define HH 16
#define DD 64
#define BR 256         // query rows per block (4 waves x 64)
#define NQT2 (SS / BR) // 8 query tiles
#define BC 64          // keys per inner tile
#define NT (SS / BC)   // 32 key tiles
#define TILE_E (BC * DD)        // 4096 bf16 elems = 8 KB per tile
#define TILE_B (TILE_E * 2)     // 8192 bytes per tile
#define LOG2E 1.44269504f
#define OSZ (BB * SS * HH * DD)   // 4M output elems
#define VSTR 516       // prep V LDS row stride (ushorts, %4==0 for 8B stores)

typedef __attribute__((ext_vector_type(8))) short short8;
typedef __attribute__((ext_vector_type(4))) float f32x4;
typedef __attribute__((ext_vector_type(16))) float f32x16;
typedef __attribute__((ext_vector_type(4))) unsigned int uint32x4;
typedef __attribute__((ext_vector_type(4))) unsigned short ushort4_t;

// fp32 -> bf16 RNE (fallback path)
static __device__ __forceinline__ unsigned short f2bf(float f) {
    unsigned int u = __float_as_uint(f);
    unsigned int r = u + 0x7FFFu + ((u >> 16) & 1u);
    return (unsigned short)(r >> 16);
}
// fp32 pair -> packed bf16x2 via single v_cvt_pk_bf16_f32 (RNE, same bits as f2bf)
static __device__ __forceinline__ unsigned int cvtpk(float lo, float hi) {
    unsigned int r;
    asm("v_cvt_pk_bf16_f32 %0, %1, %2" : "=v"(r) : "v"(lo), "v"(hi));
    return r;
}
// swap upper 32 lanes of a with lower 32 lanes of b (one VALU op, no LDS pipe)
static __device__ __forceinline__ void pl32swap(unsigned int &a, unsigned int &b) {
#if __has_builtin(__builtin_amdgcn_permlane32_swap)
    const auto r = __builtin_amdgcn_permlane32_swap((int)a, (int)b, false, false);
    a = (unsigned int)r[0];
    b = (unsigned int)r[1];
#else
    asm("v_permlane32_swap_b32 %0, %1" : "+v"(a), "+v"(b));
#endif
}
static __device__ __forceinline__ float fexp2(float x) {
#if __has_builtin(__builtin_amdgcn_exp2f)
    return __builtin_amdgcn_exp2f(x);
#else
    return exp2f(x);
#endif
}
// async global->LDS, 16B per lane
static __device__ __forceinline__ void gl_lds16(const void* g, void* l) {
    __builtin_amdgcn_global_load_lds(
        (const __attribute__((address_space(1))) void*)g,
        (__attribute__((address_space(3))) void*)l, 16, 0, 0);
}

// ---------------------------------------------------------------------------
// Pre-pass (R13: BOTH sides coalesced). Block = (b, t, hg) where hg selects
// heads hg*8..hg*8+7 (grid 128). Reads: 2KB contiguous half-rows (float4/lane,
// 512B/wave bursts). K: convert in-register, write each head's tile rows as
// full 128B lines (whole 8KB K-tile contiguous per head). V: convert into a
// [64 kv][VSTR] LDS array (conflict-free 8B writes), then write V^T tiles as
// full 128B d-rows (1KB contiguous per wave). OUTPUT BYTE-IDENTICAL to the
// R8/R11 prep: tile elem r*64 + ((c^(r&7))*8)+j, masked rows zeroed
// (exp2(0)=1 corrected via mcnt), cvtpk RNE == f2bf.
// ---------------------------------------------------------------------------
__global__ __launch_bounds__(256, 2)
void prep_kernel(const float* __restrict__ K, const float* __restrict__ V,
                 const int* __restrict__ M,
                 unsigned short* __restrict__ Kb, unsigned short* __restrict__ Vt,
                 int* __restrict__ mcnt)
{
    __shared__ unsigned short VL[64 * VSTR];   // 66,048 B

    const int blk = blockIdx.x;          // 128 blocks
    const int hg  = blk & 1;
    const int t   = (blk >> 1) & 31;
    const int b   = blk >> 6;
    const int tid = threadIdx.x;

    const int* mrow = M + (size_t)b * SS + t * BC;
    const size_t rowf = (size_t)HH * DD;               // 1024 floats per s-row
    const float* kbase = K + ((size_t)b * SS + t * BC) * rowf + hg * 512;
    const float* vbase = V + ((size_t)b * SS + t * BC) * rowf + hg * 512;

    const int w  = (tid * 4) & 511;      // float offset within row-half
    const int r0 = tid >> 7;             // 0 or 1
    const int hl = w >> 6;               // head-local 0..7
    const int d  = w & 63;
    const int h  = hg * 8 + hl;
    const int c  = d >> 3;
    const int j  = d & 7;                // 0 or 4
    const size_t ktile = ((size_t)(b * 16 + h) * NT + t) * TILE_E;

    #pragma unroll 4
    for (int i = 0; i < 32; ++i) {
        const int r = i * 2 + r0;
        const float sel = mrow[r] ? 0.0f : 1.0f;
        // K: contiguous read -> swizzled row-contiguous write (full lines)
        const float4 fk = *(const float4*)(kbase + (size_t)r * rowf + w);
        uint2 ko;
        ko.x = cvtpk(fk.x * sel, fk.y * sel);
        ko.y = cvtpk(fk.z * sel, fk.w * sel);
        *(uint2*)(Kb + ktile + r * 64 + ((c ^ (r & 7)) * 8) + j) = ko;
        // V: contiguous read -> linear LDS row (conflict-free 8B store)
        const float4 fv = *(const float4*)(vbase + (size_t)r * rowf + w);
        uint2 vo;
        vo.x = cvtpk(fv.x * sel, fv.y * sel);
        vo.y = cvtpk(fv.z * sel, fv.w * sel);
        *(uint2*)(VL + r * VSTR + w) = vo;
    }
    __syncthreads();

    // V^T write-out: full 128B d-rows, 1KB contiguous per wave iteration.
    // VL[kv*VSTR + hl*64 + d] = bf16 V[kv][h][d] (masked rows zeroed).
    #pragma unroll 4
    for (int it = 0; it < 16; ++it) {
        const int U  = it * 256 + tid;    // 0..4095
        const int g  = U & 7;             // kv-group
        const int dd = (U >> 3) & 63;     // V^T row (d)
        const int h2l = U >> 9;           // head-local
        const int col = h2l * 64 + dd;
        unsigned int wv[4];
        #pragma unroll
        for (int jp = 0; jp < 4; ++jp) {
            const unsigned int lo = VL[(g * 8 + 2 * jp + 0) * VSTR + col];
            const unsigned int hi = VL[(g * 8 + 2 * jp + 1) * VSTR + col];
            wv[jp] = lo | (hi << 16);
        }
        uint32x4 uu;
        uu[0] = wv[0]; uu[1] = wv[1]; uu[2] = wv[2]; uu[3] = wv[3];
        const size_t vtile = ((size_t)(b * 16 + hg * 8 + h2l) * NT + t) * TILE_E;
        *(uint32x4*)(Vt + vtile + dd * 64 + ((g ^ (dd & 7)) * 8)) = uu;
    }

    // masked-key count: one block per (b,t)
    if (hg == 0 && tid < 64) {
        const unsigned long long bal = __ballot(mrow[tid] != 0);
        if (tid == 0) mcnt[b * NT + t] = (int)__popcll(bal);
    }
}

// ---------------------------------------------------------------------------
// Flash kernel (unchanged from R11/R12, passing): 32x32x16 MFMA, S^T
// formulation, T12 P-redistribution, mask pre-baked into K/V, double-buffered
// staging with TWO K-tiles per barrier. Each wave owns 64 q-rows (A/B) ->
// K/V fragments read once, used twice (conflicts halved: 4.19M -> 2.10M).
// NOTE: __launch_bounds__ min-waves MUST stay 2 — (256,3) and (256,4) both
// produce wrong results (R3/R4/R5 bisect); mechanism unidentified.
// ---------------------------------------------------------------------------
__global__ __launch_bounds__(256, 2)
void fa3_kernel(const float* __restrict__ Q,
                const unsigned short* __restrict__ Kb,
                const unsigned short* __restrict__ Vt,
                const int* __restrict__ mcnt,
                float* __restrict__ Op)
{
    __shared__ __align__(16) unsigned short Ks[2][2 * TILE_E];
    __shared__ __align__(16) unsigned short Vs[2][2 * TILE_E];

    // bijective chunked XCD swizzle (grid 256, % 8 == 0)
    const int nwg  = BB * HH * NQT2;           // 256
    const int cpx  = nwg >> 3;                 // 32
    const int blk  = (blockIdx.x & 7) * cpx + (blockIdx.x >> 3);

    const int qt  = blk & (NQT2 - 1);
    const int bh  = (blk >> 3) & 31;
    const int b   = bh >> 4;
    const int h   = bh & 15;

    const int tid  = threadIdx.x;
    const int wave = tid >> 6;
    const int lane = tid & 63;
    const int ln   = lane & 31;
    const int l5   = lane >> 5;

    // ---- Q fragments for both row groups (A: rows wave*64+ln, B: +32) ----
    const float qscale = 0.125f * LOG2E;
    const int qrowA = qt * BR + wave * 64 + ln;
    const float* qpA = Q + (((size_t)b * SS + qrowA) * HH + h) * DD;
    const float* qpB = qpA + (size_t)32 * HH * DD;
    short8 qfA[4], qfB[4];
    #pragma unroll
    for (int t = 0; t < 4; ++t) {
        const int d0 = t * 16 + l5 * 8;
        {
            const float4 f0 = *(const float4*)(qpA + d0);
            const float4 f1 = *(const float4*)(qpA + d0 + 4);
            uint32x4 u;
            u[0] = cvtpk(f0.x * qscale, f0.y * qscale);
            u[1] = cvtpk(f0.z * qscale, f0.w * qscale);
            u[2] = cvtpk(f1.x * qscale, f1.y * qscale);
            u[3] = cvtpk(f1.z * qscale, f1.w * qscale);
            qfA[t] = __builtin_bit_cast(short8, u);
        }
        {
            const float4 f0 = *(const float4*)(qpB + d0);
            const float4 f1 = *(const float4*)(qpB + d0 + 4);
            uint32x4 u;
            u[0] = cvtpk(f0.x * qscale, f0.y * qscale);
            u[1] = cvtpk(f0.z * qscale, f0.w * qscale);
            u[2] = cvtpk(f1.x * qscale, f1.y * qscale);
            u[3] = cvtpk(f1.z * qscale, f1.w * qscale);
            qfB[t] = __builtin_bit_cast(short8, u);
        }
    }

    // masked-key correction (full key range; uniform scalar loads)
    int corr = 0;
    for (int i = 0; i < NT; ++i) corr += mcnt[b * NT + i];

    f32x16 acc0A, acc1A, acc0B, acc1B;
    #pragma unroll
    for (int i = 0; i < 16; ++i) {
        acc0A[i] = 0.f; acc1A[i] = 0.f; acc0B[i] = 0.f; acc1B[i] = 0.f;
    }
    f32x4 lsumA4 = {0.f, 0.f, 0.f, 0.f};
    f32x4 lsumB4 = {0.f, 0.f, 0.f, 0.f};

    const unsigned short* kb_bh = Kb + (size_t)bh * NT * TILE_E;
    const unsigned short* vt_bh = Vt + (size_t)bh * NT * TILE_E;
    const int we = wave * 1024;   // elems: wave's quarter of one tile
    const int wb = wave * 2048;   // bytes

    // ---- prologue: stage first tile PAIR into buffer 0 ----
    {
        const unsigned short* kbt = kb_bh;
        const unsigned short* vtt = vt_bh;
        #pragma unroll
        for (int s = 0; s < 2; ++s) {
            gl_lds16(kbt + s * TILE_E + we + lane * 8,       (char*)Ks[0] + s * TILE_B + wb);
            gl_lds16(kbt + s * TILE_E + we + 512 + lane * 8, (char*)Ks[0] + s * TILE_B + wb + 1024);
            gl_lds16(vtt + s * TILE_E + we + lane * 8,       (char*)Vs[0] + s * TILE_B + wb);
            gl_lds16(vtt + s * TILE_E + we + 512 + lane * 8, (char*)Vs[0] + s * TILE_B + wb + 1024);
        }
    }
    __syncthreads();

    const int pswz = (ln & 7);
    const int npair = NT >> 1;

    // SM helper: s0/s1 (32 p-values) -> pf[4] bf16 fragments + lsum update
    auto softmax_pack = [&](const f32x16& s0, const f32x16& s1,
                            f32x4& lsum4, short8* pf) {
        unsigned int pk[2][8];
        #pragma unroll
        for (int hh = 0; hh < 2; ++hh) {
            #pragma unroll
            for (int g = 0; g < 4; ++g) {
                const float p0 = fexp2(hh ? s1[g * 4 + 0] : s0[g * 4 + 0]);
                const float p1 = fexp2(hh ? s1[g * 4 + 1] : s0[g * 4 + 1]);
                const float p2 = fexp2(hh ? s1[g * 4 + 2] : s0[g * 4 + 2]);
                const float p3 = fexp2(hh ? s1[g * 4 + 3] : s0[g * 4 + 3]);
                lsum4 += (f32x4){p0, p1, p2, p3};
                pk[hh][g * 2 + 0] = cvtpk(p0, p1);
                pk[hh][g * 2 + 1] = cvtpk(p2, p3);
            }
        }
        #pragma unroll
        for (int hh = 0; hh < 2; ++hh) {
            pl32swap(pk[hh][0], pk[hh][2]);
            pl32swap(pk[hh][1], pk[hh][3]);
            pl32swap(pk[hh][4], pk[hh][6]);
            pl32swap(pk[hh][5], pk[hh][7]);
        }
        #pragma unroll
        for (int t = 0; t < 4; ++t) {
            const int hh = t >> 1;
            const int s4 = (t & 1) * 4;
            uint32x4 u;
            u[0] = pk[hh][s4 + 0];
            u[1] = pk[hh][s4 + 1];
            u[2] = pk[hh][s4 + 2];
            u[3] = pk[hh][s4 + 3];
            pf[t] = __builtin_bit_cast(short8, u);
        }
    };

    for (int ii = 0; ii < npair; ++ii) {
        const int cur = ii & 1;
        const int nxt = cur ^ 1;
        const int kn = 2 * ((ii + 1 < npair) ? ii + 1 : ii);
        const unsigned short* kbt = kb_bh + (size_t)kn * TILE_E;
        const unsigned short* vtt = vt_bh + (size_t)kn * TILE_E;
        #pragma unroll
        for (int s = 0; s < 2; ++s) {
            gl_lds16(kbt + s * TILE_E + we + lane * 8,       (char*)Ks[nxt] + s * TILE_B + wb);
            gl_lds16(kbt + s * TILE_E + we + 512 + lane * 8, (char*)Ks[nxt] + s * TILE_B + wb + 1024);
            gl_lds16(vtt + s * TILE_E + we + lane * 8,       (char*)Vs[nxt] + s * TILE_B + wb);
            gl_lds16(vtt + s * TILE_E + we + 512 + lane * 8, (char*)Vs[nxt] + s * TILE_B + wb + 1024);
        }

        #pragma unroll
        for (int sub = 0; sub < 2; ++sub) {
            const unsigned short* Kt = Ks[cur] + sub * TILE_E;
            const unsigned short* Vtl = Vs[cur] + sub * TILE_E;

            // ---- QK^T: K frags read ONCE, used for both q-groups ----
            f32x16 sA0, sA1, sB0, sB1;
            #pragma unroll
            for (int i = 0; i < 16; ++i) {
                sA0[i] = 0.f; sA1[i] = 0.f; sB0[i] = 0.f; sB1[i] = 0.f;
            }
            #pragma unroll
            for (int t = 0; t < 4; ++t) {
                const int p = (2 * t + l5) ^ pswz;
                const short8 kf0 = *(const short8*)(Kt + ln * 64 + p * 8);
                const short8 kf1 = *(const short8*)(Kt + (32 + ln) * 64 + p * 8);
                sA0 = __builtin_amdgcn_mfma_f32_32x32x16_bf16(kf0, qfA[t], sA0, 0, 0, 0);
                sA1 = __builtin_amdgcn_mfma_f32_32x32x16_bf16(kf1, qfA[t], sA1, 0, 0, 0);
                sB0 = __builtin_amdgcn_mfma_f32_32x32x16_bf16(kf0, qfB[t], sB0, 0, 0, 0);
                sB1 = __builtin_amdgcn_mfma_f32_32x32x16_bf16(kf1, qfB[t], sB1, 0, 0, 0);
            }

            // ---- softmax both groups ----
            short8 pfA[4], pfB[4];
            softmax_pack(sA0, sA1, lsumA4, pfA);
            softmax_pack(sB0, sB1, lsumB4, pfB);

            // ---- PV: V frags read ONCE, used for both q-groups ----
            #pragma unroll
            for (int t = 0; t < 4; ++t) {
                const int p = (2 * t + l5) ^ pswz;
                const short8 vf0 = *(const short8*)(Vtl + ln * 64 + p * 8);
                const short8 vf1 = *(const short8*)(Vtl + (32 + ln) * 64 + p * 8);
                acc0A = __builtin_amdgcn_mfma_f32_32x32x16_bf16(vf0, pfA[t], acc0A, 0, 0, 0);
                acc1A = __builtin_amdgcn_mfma_f32_32x32x16_bf16(vf1, pfA[t], acc1A, 0, 0, 0);
                acc0B = __builtin_amdgcn_mfma_f32_32x32x16_bf16(vf0, pfB[t], acc0B, 0, 0, 0);
                acc1B = __builtin_amdgcn_mfma_f32_32x32x16_bf16(vf1, pfB[t], acc1B, 0, 0, 0);
            }
        }

        __syncthreads();
    }

    // ---- epilogue: two row groups ----
    const float lsA = (lsumA4[0] + lsumA4[1]) + (lsumA4[2] + lsumA4[3]);
    const float lsB = (lsumB4[0] + lsumB4[1]) + (lsumB4[2] + lsumB4[3]);
    const float lA = lsA + __shfl_xor(lsA, 32) - (float)corr;
    const float lB = lsB + __shfl_xor(lsB, 32) - (float)corr;
    {
        const float inv = 1.0f / lA;
        float* op = Op + (((size_t)b * SS + qrowA) * HH + h) * DD;
        #pragma unroll
        for (int dh = 0; dh < 2; ++dh) {
            #pragma unroll
            for (int g = 0; g < 4; ++g) {
                const int d0 = dh * 32 + 8 * g + 4 * l5;
                float4 o;
                o.x = (dh ? acc1A[g * 4 + 0] : acc0A[g * 4 + 0]) * inv;
                o.y = (dh ? acc1A[g * 4 + 1] : acc0A[g * 4 + 1]) * inv;
                o.z = (dh ? acc1A[g * 4 + 2] : acc0A[g * 4 + 2]) * inv;
                o.w = (dh ? acc1A[g * 4 + 3] : acc0A[g * 4 + 3]) * inv;
                *(float4*)(op + d0) = o;
            }
        }
    }
    {
        const float inv = 1.0f / lB;
        float* op = Op + (((size_t)b * SS + qrowA + 32) * HH + h) * DD;
        #pragma unroll
        for (int dh = 0; dh < 2; ++dh) {
            #pragma unroll
            for (int g = 0; g < 4; ++g) {
                const int d0 = dh * 32 + 8 * g + 4 * l5;
                float4 o;
                o.x = (dh ? acc1B[g * 4 + 0] : acc0B[g * 4 + 0]) * inv;
                o.y = (dh ? acc1B[g * 4 + 1] : acc0B[g * 4 + 1]) * inv;
                o.z = (dh ? acc1B[g * 4 + 2] : acc0B[g * 4 + 2]) * inv;
                o.w = (dh ? acc1B[g * 4 + 3] : acc0B[g * 4 + 3]) * inv;
                *(float4*)(op + d0) = o;
            }
        }
    }
}

// ---------------------------------------------------------------------------
// Fallback (round-1 kernel, known-good) if workspace is too small.
// ---------------------------------------------------------------------------
#define KP 72
#define FBR 64
__global__ __launch_bounds__(256, 2)
void fa_fallback(const float* __restrict__ Q, const float* __restrict__ K,
                 const float* __restrict__ V, const int* __restrict__ M,
                 float* __restrict__ O)
{
    __shared__ unsigned short KsF[BC][KP];
    __shared__ unsigned short VsF[DD][KP];
    __shared__ unsigned short PsF[4][16][KP];
    __shared__ float mb[BC];

    const int blk = blockIdx.x;
    const int qt = blk % (SS / FBR);
    const int bh = blk / (SS / FBR);
    const int b = bh / HH;
    const int h = bh % HH;
    const int tid = threadIdx.x;
    const int wave = tid >> 6;
    const int lane = tid & 63;
    const int lq = lane & 15;
    const int quad = lane >> 4;

    const int qrow = qt * FBR + wave * 16 + lq;
    const float* qp = Q + (((size_t)b * SS + qrow) * HH + h) * DD;
    short8 qf[2];
    #pragma unroll
    for (int c = 0; c < 2; ++c) {
        const float4 f0 = *(const float4*)(qp + c * 32 + quad * 8);
        const float4 f1 = *(const float4*)(qp + c * 32 + quad * 8 + 4);
        short8 t;
        t[0] = (short)f2bf(f0.x * 0.125f); t[1] = (short)f2bf(f0.y * 0.125f);
        t[2] = (short)f2bf(f0.z * 0.125f); t[3] = (short)f2bf(f0.w * 0.125f);
        t[4] = (short)f2bf(f1.x * 0.125f); t[5] = (short)f2bf(f1.y * 0.125f);
        t[6] = (short)f2bf(f1.z * 0.125f); t[7] = (short)f2bf(f1.w * 0.125f);
        qf[c] = t;
    }
    f32x4 acc[4];
    #pragma unroll
    for (int dt = 0; dt < 4; ++dt) acc[dt] = (f32x4){0.f, 0.f, 0.f, 0.f};
    float m_i[4] = {-1e30f, -1e30f, -1e30f, -1e30f};
    float l_i[4] = {0.f, 0.f, 0.f, 0.f};

    const int sr = tid >> 2;
    const int sc = tid & 3;
    const size_t rowstride = (size_t)HH * DD;
    const float* kbase = K + (((size_t)b * SS) * HH + h) * DD;
    const float* vbase = V + (((size_t)b * SS) * HH + h) * DD;

    for (int kt = 0; kt < NT; ++kt) {
        const int k0 = kt * BC;
        __syncthreads();
        {
            const float* kp = kbase + (size_t)(k0 + sr) * rowstride + sc * 16;
            #pragma unroll
            for (int i = 0; i < 4; ++i) {
                const float4 f = *(const float4*)(kp + i * 4);
                ushort4_t u;
                u[0] = f2bf(f.x); u[1] = f2bf(f.y); u[2] = f2bf(f.z); u[3] = f2bf(f.w);
                *(ushort4_t*)&KsF[sr][sc * 16 + i * 4] = u;
            }
            const float* vp = vbase + (size_t)(k0 + sr) * rowstride + sc * 16;
            #pragma unroll
            for (int i = 0; i < 4; ++i) {
                const float4 f = *(const float4*)(vp + i * 4);
                const int d = sc * 16 + i * 4;
                VsF[d + 0][sr] = f2bf(f.x); VsF[d + 1][sr] = f2bf(f.y);
                VsF[d + 2][sr] = f2bf(f.z); VsF[d + 3][sr] = f2bf(f.w);
            }
            if (tid < BC) mb[tid] = M[(size_t)b * SS + k0 + tid] ? -1e30f : 0.0f;
        }
        __syncthreads();
        f32x4 s[4];
        #pragma unroll
        for (int ct = 0; ct < 4; ++ct) {
            f32x4 z = (f32x4){0.f, 0.f, 0.f, 0.f};
            const unsigned short* kr = &KsF[ct * 16 + lq][quad * 8];
            const short8 kf0 = *(const short8*)kr;
            const short8 kf1 = *(const short8*)(kr + 32);
            z = __builtin_amdgcn_mfma_f32_16x16x32_bf16(qf[0], kf0, z, 0, 0, 0);
            z = __builtin_amdgcn_mfma_f32_16x16x32_bf16(qf[1], kf1, z, 0, 0, 0);
            s[ct] = z;
        }
        #pragma unroll
        for (int ct = 0; ct < 4; ++ct) {
            const float mbias = mb[ct * 16 + lq];
            s[ct][0] += mbias; s[ct][1] += mbias; s[ct][2] += mbias; s[ct][3] += mbias;
        }
        #pragma unroll
        for (int r = 0; r < 4; ++r) {
            float mx = fmaxf(fmaxf(s[0][r], s[1][r]), fmaxf(s[2][r], s[3][r]));
            mx = fmaxf(mx, __shfl_xor(mx, 1));
            mx = fmaxf(mx, __shfl_xor(mx, 2));
            mx = fmaxf(mx, __shfl_xor(mx, 4));
            mx = fmaxf(mx, __shfl_xor(mx, 8));
            const float m_new = fmaxf(m_i[r], mx);
            const float alpha = __expf(m_i[r] - m_new);
            m_i[r] = m_new;
            float rs = 0.f;
            #pragma unroll
            for (int ct = 0; ct < 4; ++ct) {
                const float p = __expf(s[ct][r] - m_new);
                rs += p;
                PsF[wave][quad * 4 + r][ct * 16 + lq] = f2bf(p);
            }
            rs += __shfl_xor(rs, 1); rs += __shfl_xor(rs, 2);
            rs += __shfl_xor(rs, 4); rs += __shfl_xor(rs, 8);
            l_i[r] = l_i[r] * alpha + rs;
            #pragma unroll
            for (int dt = 0; dt < 4; ++dt) acc[dt][r] *= alpha;
        }
        const unsigned short* pr = &PsF[wave][lq][quad * 8];
        const short8 pf0 = *(const short8*)pr;
        const short8 pf1 = *(const short8*)(pr + 32);
        #pragma unroll
        for (int dt = 0; dt < 4; ++dt) {
            const unsigned short* vr = &VsF[dt * 16 + lq][quad * 8];
            const short8 vf0 = *(const short8*)vr;
            const short8 vf1 = *(const short8*)(vr + 32);
            acc[dt] = __builtin_amdgcn_mfma_f32_16x16x32_bf16(pf0, vf0, acc[dt], 0, 0, 0);
            acc[dt] = __builtin_amdgcn_mfma_f32_16x16x32_bf16(pf1, vf1, acc[dt], 0, 0, 0);
        }
    }
    #pragma unroll
    for (int r = 0; r < 4; ++r) {
        const float inv = 1.0f / l_i[r];
        const int row = qt * FBR + wave * 16 + quad * 4 + r;
        float* op = O + (((size_t)b * SS + row) * HH + h) * DD;
        #pragma unroll
        for (int dt = 0; dt < 4; ++dt)
            op[dt * 16 + lq] = acc[dt][r] * inv;
    }
}

extern "C" void kernel_launch(void* const* d_in, const int* in_sizes, int n_in,
                              void* d_out, int out_size, void* d_ws, size_t ws_size,
                              hipStream_t stream) {
    const float* q = (const float*)d_in[0];
    const float* k = (const float*)d_in[1];
    const float* v = (const float*)d_in[2];
    const int*   m = (const int*)d_in[3];
    float* out = (float*)d_out;

    const int nprep = BB * NT * 2;                       // 128 (b, t, head-half)
    const size_t kb_bytes = (size_t)BB * HH * NT * TILE_E * 2;  // 8 MB
    const size_t mc_bytes = (size_t)BB * NT * 4;         // 256 B
    const size_t need_single = 2 * kb_bytes + mc_bytes;  // 16 MB + 256 B

    if (ws_size >= need_single) {
        unsigned short* Kb = (unsigned short*)d_ws;
        unsigned short* Vt = (unsigned short*)((char*)d_ws + kb_bytes);
        int* mcnt = (int*)((char*)d_ws + 2 * kb_bytes);
        prep_kernel<<<nprep, 256, 0, stream>>>(k, v, m, Kb, Vt, mcnt);
        fa3_kernel<<<BB * HH * NQT2, 256, 0, stream>>>(q, Kb, Vt, mcnt, out);
    } else {
        fa_fallback<<<BB * HH * (SS / FBR), 256, 0, stream>>>(q, k, v, m, out);
    }
}

// Round 14
// 135.380 us; speedup vs baseline: 1.0281x; 1.0281x over previous
//
#include <hip/hip_runtime.h>
#include <hip/hip_bf16.h>

// (B,S,H,D) = (2,2048,16,64), fp32 in/out, int32 mask (True -> -inf).
#define BB 2
#define SS 2048
#define HH 16
#define DD 64
#define BR 128         // query rows per block (4 waves x 32)
#define NQT (SS / BR)  // 16 query tiles
#define BC 64          // keys per inner tile
#define NT (SS / BC)   // 32 key tiles
#define TILE_E (BC * DD)        // 4096 bf16 elems = 8 KB per tile
#define TILE_B (TILE_E * 2)     // 8192 bytes per tile
#define LOG2E 1.44269504f
#define OSZ (BB * SS * HH * DD)   // 4M output elems
#define VSTR 516       // prep V LDS row stride (ushorts, %4==0 for 8B stores)

typedef __attribute__((ext_vector_type(8))) short short8;
typedef __attribute__((ext_vector_type(4))) float f32x4;
typedef __attribute__((ext_vector_type(16))) float f32x16;
typedef __attribute__((ext_vector_type(4))) unsigned int uint32x4;
typedef __attribute__((ext_vector_type(4))) unsigned short ushort4_t;

// fp32 -> bf16 RNE (fallback path)
static __device__ __forceinline__ unsigned short f2bf(float f) {
    unsigned int u = __float_as_uint(f);
    unsigned int r = u + 0x7FFFu + ((u >> 16) & 1u);
    return (unsigned short)(r >> 16);
}
// fp32 pair -> packed bf16x2 via single v_cvt_pk_bf16_f32 (RNE, same bits as f2bf)
static __device__ __forceinline__ unsigned int cvtpk(float lo, float hi) {
    unsigned int r;
    asm("v_cvt_pk_bf16_f32 %0, %1, %2" : "=v"(r) : "v"(lo), "v"(hi));
    return r;
}
// swap upper 32 lanes of a with lower 32 lanes of b (one VALU op, no LDS pipe)
static __device__ __forceinline__ void pl32swap(unsigned int &a, unsigned int &b) {
#if __has_builtin(__builtin_amdgcn_permlane32_swap)
    const auto r = __builtin_amdgcn_permlane32_swap((int)a, (int)b, false, false);
    a = (unsigned int)r[0];
    b = (unsigned int)r[1];
#else
    asm("v_permlane32_swap_b32 %0, %1" : "+v"(a), "+v"(b));
#endif
}
static __device__ __forceinline__ float fexp2(float x) {
#if __has_builtin(__builtin_amdgcn_exp2f)
    return __builtin_amdgcn_exp2f(x);
#else
    return exp2f(x);
#endif
}
// async global->LDS, 16B per lane
static __device__ __forceinline__ void gl_lds16(const void* g, void* l) {
    __builtin_amdgcn_global_load_lds(
        (const __attribute__((address_space(1))) void*)g,
        (__attribute__((address_space(3))) void*)l, 16, 0, 0);
}

// ---------------------------------------------------------------------------
// Pre-pass (R13 version, verified passing: BOTH sides coalesced).
// Block = (b, t, hg); reads 2KB contiguous half-rows; K written as full
// row-contiguous 128B lines per head tile; V via conflict-free LDS transpose
// then full 128B d-rows. OUTPUT BYTE-IDENTICAL across all prep versions:
// tile elem r*64 + ((c^(r&7))*8)+j, masked rows zeroed (corrected via mcnt),
// cvtpk RNE == f2bf.
// ---------------------------------------------------------------------------
__global__ __launch_bounds__(256, 2)
void prep_kernel(const float* __restrict__ K, const float* __restrict__ V,
                 const int* __restrict__ M,
                 unsigned short* __restrict__ Kb, unsigned short* __restrict__ Vt,
                 int* __restrict__ mcnt)
{
    __shared__ unsigned short VL[64 * VSTR];   // 66,048 B

    const int blk = blockIdx.x;          // 128 blocks
    const int hg  = blk & 1;
    const int t   = (blk >> 1) & 31;
    const int b   = blk >> 6;
    const int tid = threadIdx.x;

    const int* mrow = M + (size_t)b * SS + t * BC;
    const size_t rowf = (size_t)HH * DD;               // 1024 floats per s-row
    const float* kbase = K + ((size_t)b * SS + t * BC) * rowf + hg * 512;
    const float* vbase = V + ((size_t)b * SS + t * BC) * rowf + hg * 512;

    const int w  = (tid * 4) & 511;      // float offset within row-half
    const int r0 = tid >> 7;             // 0 or 1
    const int hl = w >> 6;               // head-local 0..7
    const int d  = w & 63;
    const int h  = hg * 8 + hl;
    const int c  = d >> 3;
    const int j  = d & 7;                // 0 or 4
    const size_t ktile = ((size_t)(b * 16 + h) * NT + t) * TILE_E;

    #pragma unroll 4
    for (int i = 0; i < 32; ++i) {
        const int r = i * 2 + r0;
        const float sel = mrow[r] ? 0.0f : 1.0f;
        // K: contiguous read -> swizzled row-contiguous write (full lines)
        const float4 fk = *(const float4*)(kbase + (size_t)r * rowf + w);
        uint2 ko;
        ko.x = cvtpk(fk.x * sel, fk.y * sel);
        ko.y = cvtpk(fk.z * sel, fk.w * sel);
        *(uint2*)(Kb + ktile + r * 64 + ((c ^ (r & 7)) * 8) + j) = ko;
        // V: contiguous read -> linear LDS row (conflict-free 8B store)
        const float4 fv = *(const float4*)(vbase + (size_t)r * rowf + w);
        uint2 vo;
        vo.x = cvtpk(fv.x * sel, fv.y * sel);
        vo.y = cvtpk(fv.z * sel, fv.w * sel);
        *(uint2*)(VL + r * VSTR + w) = vo;
    }
    __syncthreads();

    // V^T write-out: full 128B d-rows, 1KB contiguous per wave iteration.
    #pragma unroll 4
    for (int it = 0; it < 16; ++it) {
        const int U  = it * 256 + tid;    // 0..4095
        const int g  = U & 7;             // kv-group
        const int dd = (U >> 3) & 63;     // V^T row (d)
        const int h2l = U >> 9;           // head-local
        const int col = h2l * 64 + dd;
        unsigned int wv[4];
        #pragma unroll
        for (int jp = 0; jp < 4; ++jp) {
            const unsigned int lo = VL[(g * 8 + 2 * jp + 0) * VSTR + col];
            const unsigned int hi = VL[(g * 8 + 2 * jp + 1) * VSTR + col];
            wv[jp] = lo | (hi << 16);
        }
        uint32x4 uu;
        uu[0] = wv[0]; uu[1] = wv[1]; uu[2] = wv[2]; uu[3] = wv[3];
        const size_t vtile = ((size_t)(b * 16 + hg * 8 + h2l) * NT + t) * TILE_E;
        *(uint32x4*)(Vt + vtile + dd * 64 + ((g ^ (dd & 7)) * 8)) = uu;
    }

    // masked-key count: one block per (b,t)
    if (hg == 0 && tid < 64) {
        const unsigned long long bal = __ballot(mrow[tid] != 0);
        if (tid == 0) mcnt[b * NT + t] = (int)__popcll(bal);
    }
}

// ---------------------------------------------------------------------------
// Flash kernel (R8 version, best-measured 52.4us: 4 waves x 32 q-rows,
// grid 512 = 2 blocks/CU = 2 waves/SIMD). 32x32x16 MFMA, S^T formulation,
// T12 P-redistribution (cvt_pk_bf16 + permlane32_swap), mask pre-baked,
// double-buffered staging with TWO K-tiles per barrier. Bijective chunked
// XCD swizzle keeps each XCD's K/V slice L2-resident (FETCH 78->16MB).
// NOTE: __launch_bounds__ min-waves MUST stay 2 — (256,3) and (256,4) both
// produce wrong results (R3/R4/R5 bisect); accumulator-shape perturbations
// (R9 parity-split, R10 interleave) also miscompile. This exact body passed
// R8; do not perturb MFMA chain structure.
// ---------------------------------------------------------------------------
__global__ __launch_bounds__(256, 2)
void fa3_kernel(const float* __restrict__ Q,
                const unsigned short* __restrict__ Kb,
                const unsigned short* __restrict__ Vt,
                const int* __restrict__ mcnt,
                float* __restrict__ Op)
{
    __shared__ __align__(16) unsigned short Ks[2][2 * TILE_E];
    __shared__ __align__(16) unsigned short Vs[2][2 * TILE_E];

    // bijective chunked XCD swizzle (grid 512, % 8 == 0)
    const int nwg  = BB * HH * NQT;            // 512
    const int cpx  = nwg >> 3;                 // 64
    const int blk  = (blockIdx.x & 7) * cpx + (blockIdx.x >> 3);

    const int qt  = blk & (NQT - 1);
    const int bh  = (blk >> 4) & 31;
    const int b   = bh >> 4;
    const int h   = bh & 15;

    const int tid  = threadIdx.x;
    const int wave = tid >> 6;
    const int lane = tid & 63;
    const int ln   = lane & 31;
    const int l5   = lane >> 5;

    // ---- Q fragments: B-operand B[k=d][n=q], n=ln, k=l5*8+j per d-step ----
    const float qscale = 0.125f * LOG2E;
    const int qrow = qt * BR + wave * 32 + ln;
    const float* qp = Q + (((size_t)b * SS + qrow) * HH + h) * DD;
    short8 qf[4];
    #pragma unroll
    for (int t = 0; t < 4; ++t) {
        const int d0 = t * 16 + l5 * 8;
        const float4 f0 = *(const float4*)(qp + d0);
        const float4 f1 = *(const float4*)(qp + d0 + 4);
        uint32x4 u;
        u[0] = cvtpk(f0.x * qscale, f0.y * qscale);
        u[1] = cvtpk(f0.z * qscale, f0.w * qscale);
        u[2] = cvtpk(f1.x * qscale, f1.y * qscale);
        u[3] = cvtpk(f1.z * qscale, f1.w * qscale);
        qf[t] = __builtin_bit_cast(short8, u);
    }

    // masked-key correction (uniform scalar loads)
    int corr = 0;
    for (int i = 0; i < NT; ++i) corr += mcnt[b * NT + i];

    f32x16 acc0, acc1;
    #pragma unroll
    for (int i = 0; i < 16; ++i) { acc0[i] = 0.f; acc1[i] = 0.f; }
    f32x4 lsum4 = {0.f, 0.f, 0.f, 0.f};

    const unsigned short* kb_bh = Kb + (size_t)bh * NT * TILE_E;
    const unsigned short* vt_bh = Vt + (size_t)bh * NT * TILE_E;
    const int we = wave * 1024;   // elems: wave's quarter of one tile
    const int wb = wave * 2048;   // bytes

    // ---- prologue: stage first tile PAIR into buffer 0 ----
    {
        const unsigned short* kbt = kb_bh;
        const unsigned short* vtt = vt_bh;
        #pragma unroll
        for (int s = 0; s < 2; ++s) {
            gl_lds16(kbt + s * TILE_E + we + lane * 8,       (char*)Ks[0] + s * TILE_B + wb);
            gl_lds16(kbt + s * TILE_E + we + 512 + lane * 8, (char*)Ks[0] + s * TILE_B + wb + 1024);
            gl_lds16(vtt + s * TILE_E + we + lane * 8,       (char*)Vs[0] + s * TILE_B + wb);
            gl_lds16(vtt + s * TILE_E + we + 512 + lane * 8, (char*)Vs[0] + s * TILE_B + wb + 1024);
        }
    }
    __syncthreads();

    const int pswz = (ln & 7);
    const int npair = NT >> 1;

    for (int ii = 0; ii < npair; ++ii) {
        const int cur = ii & 1;
        const int nxt = cur ^ 1;
        const int kn = 2 * ((ii + 1 < npair) ? ii + 1 : ii);
        const unsigned short* kbt = kb_bh + (size_t)kn * TILE_E;
        const unsigned short* vtt = vt_bh + (size_t)kn * TILE_E;
        #pragma unroll
        for (int s = 0; s < 2; ++s) {
            gl_lds16(kbt + s * TILE_E + we + lane * 8,       (char*)Ks[nxt] + s * TILE_B + wb);
            gl_lds16(kbt + s * TILE_E + we + 512 + lane * 8, (char*)Ks[nxt] + s * TILE_B + wb + 1024);
            gl_lds16(vtt + s * TILE_E + we + lane * 8,       (char*)Vs[nxt] + s * TILE_B + wb);
            gl_lds16(vtt + s * TILE_E + we + 512 + lane * 8, (char*)Vs[nxt] + s * TILE_B + wb + 1024);
        }

        #pragma unroll
        for (int sub = 0; sub < 2; ++sub) {
            const unsigned short* Kt = Ks[cur] + sub * TILE_E;
            const unsigned short* Vtl = Vs[cur] + sub * TILE_E;

            // ---- S^T = K Q^T ----
            f32x16 s0, s1;
            #pragma unroll
            for (int i = 0; i < 16; ++i) { s0[i] = 0.f; s1[i] = 0.f; }
            #pragma unroll
            for (int t = 0; t < 4; ++t) {
                const int p = (2 * t + l5) ^ pswz;
                const short8 kf0 = *(const short8*)(Kt + ln * 64 + p * 8);
                const short8 kf1 = *(const short8*)(Kt + (32 + ln) * 64 + p * 8);
                s0 = __builtin_amdgcn_mfma_f32_32x32x16_bf16(kf0, qf[t], s0, 0, 0, 0);
                s1 = __builtin_amdgcn_mfma_f32_32x32x16_bf16(kf1, qf[t], s1, 0, 0, 0);
            }

            // ---- exp2 + lsum (v_pk_add_f32) + pack (v_cvt_pk_bf16_f32) ----
            unsigned int pk[2][8];
            #pragma unroll
            for (int hh = 0; hh < 2; ++hh) {
                #pragma unroll
                for (int g = 0; g < 4; ++g) {
                    const float p0 = fexp2(hh ? s1[g * 4 + 0] : s0[g * 4 + 0]);
                    const float p1 = fexp2(hh ? s1[g * 4 + 1] : s0[g * 4 + 1]);
                    const float p2 = fexp2(hh ? s1[g * 4 + 2] : s0[g * 4 + 2]);
                    const float p3 = fexp2(hh ? s1[g * 4 + 3] : s0[g * 4 + 3]);
                    lsum4 += (f32x4){p0, p1, p2, p3};
                    pk[hh][g * 2 + 0] = cvtpk(p0, p1);
                    pk[hh][g * 2 + 1] = cvtpk(p2, p3);
                }
            }
            // ---- cross-half redistribution: 8 permlane32_swap ----
            #pragma unroll
            for (int hh = 0; hh < 2; ++hh) {
                pl32swap(pk[hh][0], pk[hh][2]);
                pl32swap(pk[hh][1], pk[hh][3]);
                pl32swap(pk[hh][4], pk[hh][6]);
                pl32swap(pk[hh][5], pk[hh][7]);
            }
            short8 pf[4];
            #pragma unroll
            for (int t = 0; t < 4; ++t) {
                const int hh = t >> 1;
                const int s4 = (t & 1) * 4;
                uint32x4 u;
                u[0] = pk[hh][s4 + 0];
                u[1] = pk[hh][s4 + 1];
                u[2] = pk[hh][s4 + 2];
                u[3] = pk[hh][s4 + 3];
                pf[t] = __builtin_bit_cast(short8, u);
            }

            // ---- O^T += V^T P^T ----
            #pragma unroll
            for (int t = 0; t < 4; ++t) {
                const int p = (2 * t + l5) ^ pswz;
                const short8 vf0 = *(const short8*)(Vtl + ln * 64 + p * 8);
                const short8 vf1 = *(const short8*)(Vtl + (32 + ln) * 64 + p * 8);
                acc0 = __builtin_amdgcn_mfma_f32_32x32x16_bf16(vf0, pf[t], acc0, 0, 0, 0);
                acc1 = __builtin_amdgcn_mfma_f32_32x32x16_bf16(vf1, pf[t], acc1, 0, 0, 0);
            }
        }

        __syncthreads();
    }

    // ---- epilogue ----
    const float lsum = (lsum4[0] + lsum4[1]) + (lsum4[2] + lsum4[3]);
    const float l = lsum + __shfl_xor(lsum, 32) - (float)corr;
    const float inv = 1.0f / l;
    float* op = Op + (((size_t)b * SS + qrow) * HH + h) * DD;
    #pragma unroll
    for (int dh = 0; dh < 2; ++dh) {
        #pragma unroll
        for (int g = 0; g < 4; ++g) {
            const int d0 = dh * 32 + 8 * g + 4 * l5;
            float4 o;
            o.x = (dh ? acc1[g * 4 + 0] : acc0[g * 4 + 0]) * inv;
            o.y = (dh ? acc1[g * 4 + 1] : acc0[g * 4 + 1]) * inv;
            o.z = (dh ? acc1[g * 4 + 2] : acc0[g * 4 + 2]) * inv;
            o.w = (dh ? acc1[g * 4 + 3] : acc0[g * 4 + 3]) * inv;
            *(float4*)(op + d0) = o;
        }
    }
}

// ---------------------------------------------------------------------------
// Fallback (round-1 kernel, known-good) if workspace is too small.
// ---------------------------------------------------------------------------
#define KP 72
#define FBR 64
__global__ __launch_bounds__(256, 2)
void fa_fallback(const float* __restrict__ Q, const float* __restrict__ K,
                 const float* __restrict__ V, const int* __restrict__ M,
                 float* __restrict__ O)
{
    __shared__ unsigned short KsF[BC][KP];
    __shared__ unsigned short VsF[DD][KP];
    __shared__ unsigned short PsF[4][16][KP];
    __shared__ float mb[BC];

    const int blk = blockIdx.x;
    const int qt = blk % (SS / FBR);
    const int bh = blk / (SS / FBR);
    const int b = bh / HH;
    const int h = bh % HH;
    const int tid = threadIdx.x;
    const int wave = tid >> 6;
    const int lane = tid & 63;
    const int lq = lane & 15;
    const int quad = lane >> 4;

    const int qrow = qt * FBR + wave * 16 + lq;
    const float* qp = Q + (((size_t)b * SS + qrow) * HH + h) * DD;
    short8 qf[2];
    #pragma unroll
    for (int c = 0; c < 2; ++c) {
        const float4 f0 = *(const float4*)(qp + c * 32 + quad * 8);
        const float4 f1 = *(const float4*)(qp + c * 32 + quad * 8 + 4);
        short8 t;
        t[0] = (short)f2bf(f0.x * 0.125f); t[1] = (short)f2bf(f0.y * 0.125f);
        t[2] = (short)f2bf(f0.z * 0.125f); t[3] = (short)f2bf(f0.w * 0.125f);
        t[4] = (short)f2bf(f1.x * 0.125f); t[5] = (short)f2bf(f1.y * 0.125f);
        t[6] = (short)f2bf(f1.z * 0.125f); t[7] = (short)f2bf(f1.w * 0.125f);
        qf[c] = t;
    }
    f32x4 acc[4];
    #pragma unroll
    for (int dt = 0; dt < 4; ++dt) acc[dt] = (f32x4){0.f, 0.f, 0.f, 0.f};
    float m_i[4] = {-1e30f, -1e30f, -1e30f, -1e30f};
    float l_i[4] = {0.f, 0.f, 0.f, 0.f};

    const int sr = tid >> 2;
    const int sc = tid & 3;
    const size_t rowstride = (size_t)HH * DD;
    const float* kbase = K + (((size_t)b * SS) * HH + h) * DD;
    const float* vbase = V + (((size_t)b * SS) * HH + h) * DD;

    for (int kt = 0; kt < NT; ++kt) {
        const int k0 = kt * BC;
        __syncthreads();
        {
            const float* kp = kbase + (size_t)(k0 + sr) * rowstride + sc * 16;
            #pragma unroll
            for (int i = 0; i < 4; ++i) {
                const float4 f = *(const float4*)(kp + i * 4);
                ushort4_t u;
                u[0] = f2bf(f.x); u[1] = f2bf(f.y); u[2] = f2bf(f.z); u[3] = f2bf(f.w);
                *(ushort4_t*)&KsF[sr][sc * 16 + i * 4] = u;
            }
            const float* vp = vbase + (size_t)(k0 + sr) * rowstride + sc * 16;
            #pragma unroll
            for (int i = 0; i < 4; ++i) {
                const float4 f = *(const float4*)(vp + i * 4);
                const int d = sc * 16 + i * 4;
                VsF[d + 0][sr] = f2bf(f.x); VsF[d + 1][sr] = f2bf(f.y);
                VsF[d + 2][sr] = f2bf(f.z); VsF[d + 3][sr] = f2bf(f.w);
            }
            if (tid < BC) mb[tid] = M[(size_t)b * SS + k0 + tid] ? -1e30f : 0.0f;
        }
        __syncthreads();
        f32x4 s[4];
        #pragma unroll
        for (int ct = 0; ct < 4; ++ct) {
            f32x4 z = (f32x4){0.f, 0.f, 0.f, 0.f};
            const unsigned short* kr = &KsF[ct * 16 + lq][quad * 8];
            const short8 kf0 = *(const short8*)kr;
            const short8 kf1 = *(const short8*)(kr + 32);
            z = __builtin_amdgcn_mfma_f32_16x16x32_bf16(qf[0], kf0, z, 0, 0, 0);
            z = __builtin_amdgcn_mfma_f32_16x16x32_bf16(qf[1], kf1, z, 0, 0, 0);
            s[ct] = z;
        }
        #pragma unroll
        for (int ct = 0; ct < 4; ++ct) {
            const float mbias = mb[ct * 16 + lq];
            s[ct][0] += mbias; s[ct][1] += mbias; s[ct][2] += mbias; s[ct][3] += mbias;
        }
        #pragma unroll
        for (int r = 0; r < 4; ++r) {
            float mx = fmaxf(fmaxf(s[0][r], s[1][r]), fmaxf(s[2][r], s[3][r]));
            mx = fmaxf(mx, __shfl_xor(mx, 1));
            mx = fmaxf(mx, __shfl_xor(mx, 2));
            mx = fmaxf(mx, __shfl_xor(mx, 4));
            mx = fmaxf(mx, __shfl_xor(mx, 8));
            const float m_new = fmaxf(m_i[r], mx);
            const float alpha = __expf(m_i[r] - m_new);
            m_i[r] = m_new;
            float rs = 0.f;
            #pragma unroll
            for (int ct = 0; ct < 4; ++ct) {
                const float p = __expf(s[ct][r] - m_new);
                rs += p;
                PsF[wave][quad * 4 + r][ct * 16 + lq] = f2bf(p);
            }
            rs += __shfl_xor(rs, 1); rs += __shfl_xor(rs, 2);
            rs += __shfl_xor(rs, 4); rs += __shfl_xor(rs, 8);
            l_i[r] = l_i[r] * alpha + rs;
            #pragma unroll
            for (int dt = 0; dt < 4; ++dt) acc[dt][r] *= alpha;
        }
        const unsigned short* pr = &PsF[wave][lq][quad * 8];
        const short8 pf0 = *(const short8*)pr;
        const short8 pf1 = *(const short8*)(pr + 32);
        #pragma unroll
        for (int dt = 0; dt < 4; ++dt) {
            const unsigned short* vr = &VsF[dt * 16 + lq][quad * 8];
            const short8 vf0 = *(const short8*)vr;
            const short8 vf1 = *(const short8*)(vr + 32);
            acc[dt] = __builtin_amdgcn_mfma_f32_16x16x32_bf16(pf0, vf0, acc[dt], 0, 0, 0);
            acc[dt] = __builtin_amdgcn_mfma_f32_16x16x32_bf16(pf1, vf1, acc[dt], 0, 0, 0);
        }
    }
    #pragma unroll
    for (int r = 0; r < 4; ++r) {
        const float inv = 1.0f / l_i[r];
        const int row = qt * FBR + wave * 16 + quad * 4 + r;
        float* op = O + (((size_t)b * SS + row) * HH + h) * DD;
        #pragma unroll
        for (int dt = 0; dt < 4; ++dt)
            op[dt * 16 + lq] = acc[dt][r] * inv;
    }
}

extern "C" void kernel_launch(void* const* d_in, const int* in_sizes, int n_in,
                              void* d_out, int out_size, void* d_ws, size_t ws_size,
                              hipStream_t stream) {
    const float* q = (const float*)d_in[0];
    const float* k = (const float*)d_in[1];
    const float* v = (const float*)d_in[2];
    const int*   m = (const int*)d_in[3];
    float* out = (float*)d_out;

    const int nprep = BB * NT * 2;                       // 128 (b, t, head-half)
    const size_t kb_bytes = (size_t)BB * HH * NT * TILE_E * 2;  // 8 MB
    const size_t mc_bytes = (size_t)BB * NT * 4;         // 256 B
    const size_t need_single = 2 * kb_bytes + mc_bytes;  // 16 MB + 256 B

    if (ws_size >= need_single) {
        // 512 fa3 blocks = exactly 2/CU x 256 CU, one residency round,
        // no partials round-trip, no combine kernel.
        unsigned short* Kb = (unsigned short*)d_ws;
        unsigned short* Vt = (unsigned short*)((char*)d_ws + kb_bytes);
        int* mcnt = (int*)((char*)d_ws + 2 * kb_bytes);
        prep_kernel<<<nprep, 256, 0, stream>>>(k, v, m, Kb, Vt, mcnt);
        fa3_kernel<<<BB * HH * NQT, 256, 0, stream>>>(q, Kb, Vt, mcnt, out);
    } else {
        fa_fallback<<<BB * HH * (SS / FBR), 256, 0, stream>>>(q, k, v, m, out);
    }
}